// Round 7
// baseline (147.136 us; speedup 1.0000x reference)
//
#include <hip/hip_runtime.h>
#include <hip/hip_fp16.h>

// grid : (B=4, gh=16, gw=16, gd=8, nc=12)  fp32
// guide: (B=4, H=1024, W=1024)             fp32
// inp  : (B=4, H=1024, W=1024, 3)          fp32
// out  : (B=4, H=1024, W=1024, 3)          fp32
//
// Block = 64-wide x 64-row band at rows [64g-32, 64g+32) (32-row edge bands
// g=0,16). Any such band uses exactly ONE y-cell pair (g-1, g) since pair
// boundaries sit at y = 64m+31.5.
// Phase 0: cooperative coalesced load of the unique raw grid slice
//          [yc:2][xc:3][z:8][c:12] fp32 (2304 B) into LDS (3 dwords/thread).
// Phase 1: x-interp from raw LDS -> packed fp16 LDS:
//          lA [yc:2][z:8][x:64] 4x half2 (ch 0..7)  16 KB
//          lB [z:8][x:64] {ycA:(c8,c9),(c10,c11), ycB:same}  8 KB
// Phase 2: per row: 6 conflict-free ds_read_b128, y/z lerp + affine in
//          packed fp16, f32 store. guide/inp prefetched in 8-row halves,
//          each issued right AFTER a barrier so the barrier drain can't
//          eat the in-flight loads.
// LDS total 26880 B -> 6 blocks/CU.

struct __align__(16) H2x4 { __half2 x, y, z, w; };

__global__ __launch_bounds__(256, 6) void BilateralSliceApply_kernel(
    const float* __restrict__ grid,
    const float* __restrict__ guide,
    const float* __restrict__ inp,
    float* __restrict__ out)
{
    __shared__ float lraw[576];      // [yc:2][xc:3][z:8][c:12]   2304 B
    __shared__ H2x4  lA[16 * 64];    // (yc*8+z)*64 + x           16 KB
    __shared__ H2x4  lB[ 8 * 64];    // z*64 + x                   8 KB

    const int tx = blockIdx.x;       // 0..15
    const int g  = blockIdx.y;       // 0..16 (y band)
    const int b  = blockIdx.z;       // 0..3
    const int t  = threadIdx.x;      // 0..255
    const int xl = t & 63;
    const int r0 = t >> 6;           // 0..3

    const int x0     = tx << 6;
    const int ystart = (g == 0) ? 0 : ((g << 6) - 32);
    const int interior = (g != 0) & (g != 16);   // 64-row band?

    const int fy  = g - 1;
    const int ycA = fy < 0 ? 0 : fy;
    const int ycB = g > 15 ? 15 : g;

    // ---------------- phase 0: raw grid slice -> LDS (coalesced) ----------------
    const int bb16 = b << 4;
    for (int d = t; d < 576; d += 256) {
        const int yc  = d >= 288 ? 1 : 0;
        const int rem = d - (yc ? 288 : 0);
        const int xco = rem / 96;                 // 0..2
        const int wi  = rem - xco * 96;
        int cx = tx - 1 + xco;
        cx = cx < 0 ? 0 : (cx > 15 ? 15 : cx);
        const int yce = yc ? ycB : ycA;
        lraw[d] = grid[(size_t)(((bb16 + yce) << 4) + cx) * 96 + wi];
    }
    __syncthreads();

    // ---- prefetch first half of guide/inp (rows k=0..7) ----
    const int pp0 = (((b << 10) + ystart + r0) << 10) + x0 + xl;
    float  gzA[8];
    float3 inA[8];
#pragma unroll
    for (int k = 0; k < 8; ++k) {
        const int pp = pp0 + (k << 12);
        gzA[k] = guide[pp];
        inA[k] = *(const float3*)(inp + (size_t)pp * 3);
    }

    // ---------------- phase 1: x-interp (LDS -> fp16 LDS) ----------------
    const int fx  = (xl < 32) ? (tx - 1) : tx;
    const float wx1 = ((float)(x0 + xl) + 0.5f) * 0.015625f - 0.5f - (float)fx;
    const int cb = (xl < 32) ? 0 : 96;   // cell offset within yc slice

#pragma unroll
    for (int q = 0; q < 6; ++q) {
        const int L = r0 + (q << 2);     // wave-uniform, covers 0..23
        const int z = L & 7;
        if (L < 16) {
            const int yc   = L >> 3;
            const int base = yc * 288 + cb + z * 12;
            const float4 a0 = *(const float4*)&lraw[base];
            const float4 a1 = *(const float4*)&lraw[base + 4];
            const float4 b0 = *(const float4*)&lraw[base + 96];
            const float4 b1 = *(const float4*)&lraw[base + 100];
            H2x4 r;
            r.x = __floats2half2_rn(fmaf(wx1, b0.x - a0.x, a0.x),
                                    fmaf(wx1, b0.y - a0.y, a0.y));
            r.y = __floats2half2_rn(fmaf(wx1, b0.z - a0.z, a0.z),
                                    fmaf(wx1, b0.w - a0.w, a0.w));
            r.z = __floats2half2_rn(fmaf(wx1, b1.x - a1.x, a1.x),
                                    fmaf(wx1, b1.y - a1.y, a1.y));
            r.w = __floats2half2_rn(fmaf(wx1, b1.z - a1.z, a1.z),
                                    fmaf(wx1, b1.w - a1.w, a1.w));
            lA[(L << 6) + xl] = r;
        } else {
            const int base = cb + z * 12 + 8;
            const float4 aA = *(const float4*)&lraw[base];          // ycA, c8..11
            const float4 bA = *(const float4*)&lraw[base + 96];
            const float4 aB = *(const float4*)&lraw[base + 288];    // ycB, c8..11
            const float4 bB = *(const float4*)&lraw[base + 384];
            H2x4 r;
            r.x = __floats2half2_rn(fmaf(wx1, bA.x - aA.x, aA.x),
                                    fmaf(wx1, bA.y - aA.y, aA.y));
            r.y = __floats2half2_rn(fmaf(wx1, bA.z - aA.z, aA.z),
                                    fmaf(wx1, bA.w - aA.w, aA.w));
            r.z = __floats2half2_rn(fmaf(wx1, bB.x - aB.x, aB.x),
                                    fmaf(wx1, bB.y - aB.y, aB.y));
            r.w = __floats2half2_rn(fmaf(wx1, bB.z - aB.z, aB.z),
                                    fmaf(wx1, bB.w - aB.w, aB.w));
            lB[(z << 6) + xl] = r;
        }
    }
    __syncthreads();

    // ---- prefetch second half (rows k=8..15), interior bands only ----
    float  gzB[8];
    float3 inB[8];
    if (interior) {
#pragma unroll
        for (int k = 0; k < 8; ++k) {
            const int pp = pp0 + ((k + 8) << 12);
            gzB[k] = guide[pp];
            inB[k] = *(const float3*)(inp + (size_t)pp * 3);
        }
    }

    // ---------------- phase 2: y/z lerp + affine (packed fp16) ----------------
    const float wybase = ((float)(ystart + r0) + 0.5f) * 0.015625f - 0.5f - (float)fy;
    const int nk = interior ? 16 : 8;
    for (int k = 0; k < nk; ++k) {
        const int pp = pp0 + (k << 12);

        const float wy1 = wybase + (float)(k << 2) * 0.015625f;
        const float wy0 = 1.0f - wy1;

        const float gz  = (k < 8 ? gzA[k & 7] : gzB[k & 7]) * 8.0f;
        const float fz  = floorf(gz - 0.5f);
        const float wz1 = gz - 0.5f - fz;
        const float wz0 = 1.0f - wz1;
        const int ifz = (int)fz;
        const int iz0 = ifz < 0 ? 0 : (ifz > 7 ? 7 : ifz);
        const int nz  = ifz + 1;
        const int iz1 = nz < 0 ? 0 : (nz > 7 ? 7 : nz);

        const __half2 hA0 = __float2half2_rn(wy0 * wz0);
        const __half2 hA1 = __float2half2_rn(wy0 * wz1);
        const __half2 hB0 = __float2half2_rn(wy1 * wz0);
        const __half2 hB1 = __float2half2_rn(wy1 * wz1);

        const H2x4 vA00 = lA[(iz0 << 6) + xl];          // ycA, z0
        const H2x4 vA01 = lA[(iz1 << 6) + xl];          // ycA, z1
        const H2x4 vA10 = lA[((8 + iz0) << 6) + xl];    // ycB, z0
        const H2x4 vA11 = lA[((8 + iz1) << 6) + xl];    // ycB, z1
        const H2x4 vB0  = lB[(iz0 << 6) + xl];          // {ycA c8-11, ycB c8-11}, z0
        const H2x4 vB1  = lB[(iz1 << 6) + xl];

        __half2 q0 = __hmul2(hA0, vA00.x);              // (c0,c1)
        __half2 q1 = __hmul2(hA0, vA00.y);              // (c2,c3)
        __half2 q2 = __hmul2(hA0, vA00.z);              // (c4,c5)
        __half2 q3 = __hmul2(hA0, vA00.w);              // (c6,c7)
        q0 = __hfma2(hA1, vA01.x, q0);
        q1 = __hfma2(hA1, vA01.y, q1);
        q2 = __hfma2(hA1, vA01.z, q2);
        q3 = __hfma2(hA1, vA01.w, q3);
        q0 = __hfma2(hB0, vA10.x, q0);
        q1 = __hfma2(hB0, vA10.y, q1);
        q2 = __hfma2(hB0, vA10.z, q2);
        q3 = __hfma2(hB0, vA10.w, q3);
        q0 = __hfma2(hB1, vA11.x, q0);
        q1 = __hfma2(hB1, vA11.y, q1);
        q2 = __hfma2(hB1, vA11.z, q2);
        q3 = __hfma2(hB1, vA11.w, q3);

        __half2 q4 = __hmul2(hA0, vB0.x);               // (c8,c9)
        __half2 q5 = __hmul2(hA0, vB0.y);               // (c10,c11)
        q4 = __hfma2(hA1, vB1.x, q4);
        q5 = __hfma2(hA1, vB1.y, q5);
        q4 = __hfma2(hB0, vB0.z, q4);
        q5 = __hfma2(hB0, vB0.w, q5);
        q4 = __hfma2(hB1, vB1.z, q4);
        q5 = __hfma2(hB1, vB1.w, q5);

        const float3 in = (k < 8) ? inA[k & 7] : inB[k & 7];
        const __half2 i01 = __floats2half2_rn(in.x, in.y);
        const __half2 i21 = __floats2half2_rn(in.z, 1.0f);

        __half2 r0h = __hmul2(q0, i01); r0h = __hfma2(q1, i21, r0h);
        __half2 r1h = __hmul2(q2, i01); r1h = __hfma2(q3, i21, r1h);
        __half2 r2h = __hmul2(q4, i01); r2h = __hfma2(q5, i21, r2h);

        float3 o;
        o.x = __low2float(r0h) + __high2float(r0h);
        o.y = __low2float(r1h) + __high2float(r1h);
        o.z = __low2float(r2h) + __high2float(r2h);
        *(float3*)(out + (size_t)pp * 3) = o;
    }
}

extern "C" void kernel_launch(void* const* d_in, const int* in_sizes, int n_in,
                              void* d_out, int out_size, void* d_ws, size_t ws_size,
                              hipStream_t stream) {
    const float* grid  = (const float*)d_in[0];
    const float* guide = (const float*)d_in[1];
    const float* inp   = (const float*)d_in[2];
    float* out = (float*)d_out;

    dim3 gridDim(16, 17, 4);   // x tiles, y bands (offset by -32), batch
    BilateralSliceApply_kernel<<<gridDim, 256, 0, stream>>>(grid, guide, inp, out);
}